// Round 16
// baseline (234.789 us; speedup 1.0000x reference)
//
#include <hip/hip_runtime.h>
#include <math.h>

constexpr int NN  = 50000;
constexpr int NE  = 800000;
constexpr int NNP = 50048;             // padded rows = 391 * 128
constexpr int NB  = (NN + 255) / 256;  // scan blocks
constexpr int GX  = NNP / 128;         // 391 GEMM row tiles
constexpr int NTOT  = 448;             // 56 groups of 8 blocks
constexpr int NFILL = NTOT / 8;        // 56 fill blocks (bid%8==0 -> one XCD)

typedef __bf16 bf16x8 __attribute__((ext_vector_type(8)));
typedef float  f32x4  __attribute__((ext_vector_type(4)));
typedef __attribute__((address_space(1))) unsigned int as1_uint;
typedef __attribute__((address_space(3))) unsigned int as3_uint;

__device__ __forceinline__ unsigned short f2bf(float x) {  // RNE fp32->bf16 bits
    unsigned int u = __float_as_uint(x);
    return (unsigned short)((u + 0x7FFFu + ((u >> 16) & 1u)) >> 16);
}
__device__ __forceinline__ float bf2f(unsigned short h) {
    return __uint_as_float(((unsigned int)h) << 16);
}
__device__ __forceinline__ float rdlanef(float v, int j) {
    return __uint_as_float(__builtin_amdgcn_readlane(__float_as_uint(v), j));
}

__device__ __forceinline__ void gload16(const unsigned short* g, unsigned short* l) {
    __builtin_amdgcn_global_load_lds((const as1_uint*)(unsigned long long)g,
                                     (as3_uint*)(unsigned long long)l, 16, 0, 0);
}

// ---------------- CSR build ----------------
__global__ void k_bsum(const int* __restrict__ cnt, int* __restrict__ bsum) {
    int i = blockIdx.x * 256 + threadIdx.x;
    int v = (i < NN) ? cnt[i] : 0;
#pragma unroll
    for (int off = 32; off; off >>= 1) v += __shfl_down(v, off, 64);
    __shared__ int tmp[4];
    if ((threadIdx.x & 63) == 0) tmp[threadIdx.x >> 6] = v;
    __syncthreads();
    if (threadIdx.x == 0) bsum[blockIdx.x] = tmp[0] + tmp[1] + tmp[2] + tmp[3];
}

__global__ void k_scan_bsum(const int* __restrict__ bsum, int* __restrict__ boff) {
    __shared__ int s[256];
    int t = threadIdx.x;
    int v = (t < NB) ? bsum[t] : 0;
    s[t] = v;
    __syncthreads();
    for (int off = 1; off < 256; off <<= 1) {
        int u = (t >= off) ? s[t - off] : 0;
        __syncthreads();
        s[t] += u;
        __syncthreads();
    }
    if (t < NB) boff[t] = s[t] - v;
}

// also emits dinv (folded k_dinv)
__global__ void k_scan_block(const int* __restrict__ cnt, const int* __restrict__ boff,
                             int* __restrict__ rowoff, float* __restrict__ dinv) {
    __shared__ int s[256];
    int t = threadIdx.x;
    int i = blockIdx.x * 256 + t;
    int v = (i < NN) ? cnt[i] : 0;
    s[t] = v;
    __syncthreads();
    for (int off = 1; off < 256; off <<= 1) {
        int u = (t >= off) ? s[t - off] : 0;
        __syncthreads();
        s[t] += u;
        __syncthreads();
    }
    if (i < NN) {
        rowoff[i] = boff[blockIdx.x] + s[t] - v;
        dinv[i] = rsqrtf(fmaxf((float)v, 1.0f));
    }
}

// ---------------- shfl-broadcast low_conv gather (single bf16) ----------------
// wave = 1 node, 64 lanes x ushort2 = full 256B row per load. eidx+dinv preloaded
// lane-parallel, broadcast via readlane. Predicated groups of 8 (no serial tail).
__global__ __launch_bounds__(256) void k_gather_shfl(
    const unsigned short* __restrict__ HH, const float* __restrict__ dinv,
    const int* __restrict__ rowoff, const int* __restrict__ cnt,
    const int* __restrict__ eidx, unsigned short* __restrict__ OH)
{
    int node = blockIdx.x * 4 + (threadIdx.x >> 6);
    int lane = threadIdx.x & 63;
    if (node >= NNP) return;
    size_t rb = (size_t)node * 128 + lane * 2;
    if (node >= NN) {  // zero pad rows
        *reinterpret_cast<ushort2*>(&OH[rb]) = make_ushort2(0, 0);
        return;
    }
    int beg = rowoff[node], n = cnt[node];
    int c2 = lane * 2;
    float ax = 0.f, ay = 0.f;
    for (int jj = 0; jj < n; jj += 64) {
        int m = min(n - jj, 64);
        int el = (lane < m) ? eidx[beg + jj + lane] : 0;   // pad lanes -> node 0
        float dl = dinv[el];
        int mp = (m + 7) & ~7;
        for (int j = 0; j < mp; j += 8) {
            int ss[8]; float dd[8]; ushort2 vv[8];
#pragma unroll
            for (int q = 0; q < 8; ++q) {
                int jq = (j + q) & 63;
                ss[q] = __builtin_amdgcn_readlane(el, jq);
                dd[q] = (j + q < m) ? rdlanef(dl, jq) : 0.f;   // uniform predicate
            }
#pragma unroll
            for (int q = 0; q < 8; ++q)
                vv[q] = *reinterpret_cast<const ushort2*>(&HH[(size_t)ss[q] * 128 + c2]);
#pragma unroll
            for (int q = 0; q < 8; ++q) {
                ax = fmaf(bf2f(vv[q].x), dd[q], ax);
                ay = fmaf(bf2f(vv[q].y), dd[q], ay);
            }
        }
    }
    float d = dinv[node];
    ushort2 sh = *reinterpret_cast<const ushort2*>(&HH[rb]);
    float hx = fmaf(ax, d, bf2f(sh.x));
    float hy = fmaf(ay, d, bf2f(sh.y));
    *reinterpret_cast<ushort2*>(&OH[rb]) = make_ushort2(f2bf(hx), f2bf(hy));
}

// ---------------- unified weight prep + dst histogram + slot assignment ----------------
__global__ void k_wprep_count(const float* __restrict__ W0, const float* __restrict__ W1,
                              const float* __restrict__ Wp1, const float* __restrict__ Wp2,
                              unsigned short* __restrict__ W0t, unsigned short* __restrict__ W1pt,
                              unsigned short* __restrict__ Wp2t, float* __restrict__ stats,
                              const int* __restrict__ dst, int* __restrict__ cnt,
                              int* __restrict__ pos) {
    int b = blockIdx.x, t = threadIdx.x;
    if (b >= 512) {
        int i = (b - 512) * 256 + t;
        if (i < NE) pos[i] = atomicAdd(&cnt[dst[i]], 1);
        return;
    }
    if (b < 128) {
        if (b < 2) stats[b * 256 + t] = 0.f;
        float s = 0.f;
        for (int k = 0; k < 128; ++k) s = fmaf(W1[b * 128 + k], Wp1[k * 256 + t], s);
        W1pt[t * 128 + b] = f2bf(s);
    } else if (b < 384) {
        int idx = (b - 128) * 256 + t;     // W0: K=512, N=128
        int k = idx >> 7, n = idx & 127;
        W0t[n * 512 + k] = f2bf(W0[idx]);
    } else {
        int idx = (b - 384) * 256 + t;     // Wp2: K=256, N=128
        int k = idx >> 7, n = idx & 127;
        Wp2t[n * 256 + k] = f2bf(Wp2[idx]);
    }
}

// ---------------- fused GEMM1 (feat@W0 -> bf16) + XCD-clustered CSR fill ----------------
// fill = blocks with bid%8==0 (all land on one XCD -> eidx stays L2-local there,
// no cross-XCD line bouncing); GEMM tiles take the remaining 7/8 of blocks.
__global__ __launch_bounds__(512) void k_gemm1_fill(
    const float* __restrict__ Af, const unsigned short* __restrict__ BH,
    unsigned short* __restrict__ OHs,
    const int* __restrict__ src, const int* __restrict__ dst,
    const int* __restrict__ rowoff, const int* __restrict__ pos,
    int* __restrict__ eidx)
{
    int bid = blockIdx.x;
    if ((bid & 7) == 0) {   // ---- fill path (one XCD, grid-stride, no atomics) ----
        for (int e = (bid >> 3) * 512 + threadIdx.x; e < NE; e += NFILL * 512) {
            int d = dst[e];
            eidx[rowoff[d] + pos[e]] = src[e];
        }
        return;
    }
    int gid = bid - (bid >> 3) - 1;   // compact index over non-fill blocks
    if (gid >= GX) return;
    // ---- GEMM path (K=512, NCOLS=128) ----
    constexpr int K = 512, NCOLS = 128;
    __shared__ __align__(16) unsigned short lds[2 * 4096];
    unsigned short* ldsA = lds;
    unsigned short* ldsB = lds + 4096;

    const int tid  = threadIdx.x;
    const int lane = tid & 63;
    const int wid  = tid >> 6;
    const int wm   = wid >> 1;
    const int wn   = wid & 1;
    const int row0 = gid * 128;

    const int srow  = tid >> 2;
    const int skg   = tid & 3;
    const int skswz = skg ^ ((srow >> 1) & 3);
    const size_t aSrc = (size_t)(row0 + srow) * K + skswz * 8;
    const size_t bSrc = (size_t)srow * K + skswz * 8;

    const int frow = lane & 15;
    const int fkg  = lane >> 4;

    f32x4 acc[2][4] = {};

    for (int k0 = 0; k0 < K; k0 += 32) {
        float4 f0, f1;
        if (row0 + srow < NN) {
            const float* ap = Af + aSrc + k0;
            f0 = *reinterpret_cast<const float4*>(ap);
            f1 = *reinterpret_cast<const float4*>(ap + 4);
        } else {
            f0 = make_float4(0.f, 0.f, 0.f, 0.f);
            f1 = f0;
        }
        uint4 w;
        w.x = (unsigned)f2bf(f0.x) | ((unsigned)f2bf(f0.y) << 16);
        w.y = (unsigned)f2bf(f0.z) | ((unsigned)f2bf(f0.w) << 16);
        w.z = (unsigned)f2bf(f1.x) | ((unsigned)f2bf(f1.y) << 16);
        w.w = (unsigned)f2bf(f1.z) | ((unsigned)f2bf(f1.w) << 16);
        *reinterpret_cast<uint4*>(&ldsA[tid * 8]) = w;
        gload16(BH + bSrc + k0, ldsB + tid * 8);
        __syncthreads();

        bf16x8 a_h[2], b_h[4];
#pragma unroll
        for (int mi = 0; mi < 2; ++mi) {
            int ar  = wm * 32 + mi * 16 + frow;
            int idx = ar * 32 + ((fkg ^ ((ar >> 1) & 3)) * 8);
            a_h[mi] = *reinterpret_cast<const bf16x8*>(&ldsA[idx]);
        }
#pragma unroll
        for (int ni = 0; ni < 4; ++ni) {
            int bc  = wn * 64 + ni * 16 + frow;
            int idx = bc * 32 + ((fkg ^ ((bc >> 1) & 3)) * 8);
            b_h[ni] = *reinterpret_cast<const bf16x8*>(&ldsB[idx]);
        }
#pragma unroll
        for (int mi = 0; mi < 2; ++mi)
#pragma unroll
            for (int ni = 0; ni < 4; ++ni)
                acc[mi][ni] = __builtin_amdgcn_mfma_f32_16x16x32_bf16(a_h[mi], b_h[ni], acc[mi][ni], 0, 0, 0);
        __syncthreads();
    }

#pragma unroll
    for (int mi = 0; mi < 2; ++mi) {
        int rbase = row0 + wm * 32 + mi * 16 + (lane >> 4) * 4;
#pragma unroll
        for (int ni = 0; ni < 4; ++ni) {
            int col = wn * 64 + ni * 16 + (lane & 15);
#pragma unroll
            for (int r = 0; r < 4; ++r)
                OHs[(size_t)(rbase + r) * NCOLS + col] = f2bf(acc[mi][ni][r]);
        }
    }
}

// ---------------- single-bf16 MFMA GEMM (flat layouts) ----------------
// AMODE: 0 = bf16 via global_load_lds; 2 = bf16 reg-staged + BN+ReLU (LDS-precomputed).
// OMODE: 0 = fp32 C (rows<NN); 1 = bf16 all rows. STATS: column sum/sumsq (rows<NN).
template <int K, int NCOLS, bool BIAS, int AMODE, int OMODE, bool STATS>
__global__ __launch_bounds__(512) void k_mfma(
    const unsigned short* __restrict__ AH, const unsigned short* __restrict__ BH,
    const float* __restrict__ bias,
    const float* __restrict__ stats, const float* __restrict__ gamma,
    const float* __restrict__ beta,
    float* __restrict__ C, unsigned short* __restrict__ OHs,
    float* __restrict__ statsOut)
{
    __shared__ __align__(16) unsigned short lds[2 * 4096];
    unsigned short* ldsA = lds;
    unsigned short* ldsB = lds + 4096;

    const int tid  = threadIdx.x;
    const int lane = tid & 63;
    const int wid  = tid >> 6;
    const int wm   = wid >> 1;
    const int wn   = wid & 1;
    const int row0 = blockIdx.x * 128;
    const int col0 = blockIdx.y * 128;

    const int srow  = tid >> 2;
    const int skg   = tid & 3;
    const int skswz = skg ^ ((srow >> 1) & 3);
    const size_t aSrc = (size_t)(row0 + srow) * K + skswz * 8;
    const size_t bSrc = (size_t)(col0 + srow) * K + skswz * 8;

    const int frow = lane & 15;
    const int fkg  = lane >> 4;

    __shared__ float s_scl[256], s_shf[256];
    if constexpr (AMODE == 2) {
        if (tid < K) {
            float mu  = stats[tid] * (1.0f / NN);
            float var = stats[256 + tid] * (1.0f / NN) - mu * mu;
            float s = gamma[tid] * rsqrtf(var + 1e-5f);
            s_scl[tid] = s;
            s_shf[tid] = beta[tid] - mu * s;
        }
        __syncthreads();
    }

    f32x4 acc[2][4] = {};

    for (int k0 = 0; k0 < K; k0 += 32) {
        if constexpr (AMODE == 2) {
            uint4 raw = *reinterpret_cast<const uint4*>(&AH[aSrc + k0]);
            unsigned rw[4] = {raw.x, raw.y, raw.z, raw.w};
            int kc = k0 + skswz * 8;
            float vv[8];
#pragma unroll
            for (int q = 0; q < 8; ++q) {
                float z = bf2f((unsigned short)((q & 1) ? (rw[q >> 1] >> 16)
                                                        : (rw[q >> 1] & 0xFFFF)));
                vv[q] = fmaxf(fmaf(z, s_scl[kc + q], s_shf[kc + q]), 0.f);
            }
            uint4 w;
            w.x = (unsigned)f2bf(vv[0]) | ((unsigned)f2bf(vv[1]) << 16);
            w.y = (unsigned)f2bf(vv[2]) | ((unsigned)f2bf(vv[3]) << 16);
            w.z = (unsigned)f2bf(vv[4]) | ((unsigned)f2bf(vv[5]) << 16);
            w.w = (unsigned)f2bf(vv[6]) | ((unsigned)f2bf(vv[7]) << 16);
            *reinterpret_cast<uint4*>(&ldsA[tid * 8]) = w;
        } else {
            gload16(AH + aSrc + k0, ldsA + tid * 8);
        }
        gload16(BH + bSrc + k0, ldsB + tid * 8);
        __syncthreads();

        bf16x8 a_h[2], b_h[4];
#pragma unroll
        for (int mi = 0; mi < 2; ++mi) {
            int ar  = wm * 32 + mi * 16 + frow;
            int idx = ar * 32 + ((fkg ^ ((ar >> 1) & 3)) * 8);
            a_h[mi] = *reinterpret_cast<const bf16x8*>(&ldsA[idx]);
        }
#pragma unroll
        for (int ni = 0; ni < 4; ++ni) {
            int bc  = wn * 64 + ni * 16 + frow;
            int idx = bc * 32 + ((fkg ^ ((bc >> 1) & 3)) * 8);
            b_h[ni] = *reinterpret_cast<const bf16x8*>(&ldsB[idx]);
        }
#pragma unroll
        for (int mi = 0; mi < 2; ++mi)
#pragma unroll
            for (int ni = 0; ni < 4; ++ni)
                acc[mi][ni] = __builtin_amdgcn_mfma_f32_16x16x32_bf16(a_h[mi], b_h[ni], acc[mi][ni], 0, 0, 0);
        __syncthreads();
    }

    float psum[4] = {0.f, 0.f, 0.f, 0.f}, psq[4] = {0.f, 0.f, 0.f, 0.f};
#pragma unroll
    for (int mi = 0; mi < 2; ++mi) {
        int rbase = row0 + wm * 32 + mi * 16 + (lane >> 4) * 4;
#pragma unroll
        for (int ni = 0; ni < 4; ++ni) {
            int col = col0 + wn * 64 + ni * 16 + (lane & 15);
            float b = BIAS ? bias[col] : 0.f;
#pragma unroll
            for (int r = 0; r < 4; ++r) {
                int row = rbase + r;
                float v = acc[mi][ni][r] + b;
                if constexpr (STATS) {
                    if (row < NN) { psum[ni] += v; psq[ni] = fmaf(v, v, psq[ni]); }
                }
                if constexpr (OMODE == 1) {
                    OHs[(size_t)row * NCOLS + col] = f2bf(v);   // pad rows too
                } else {
                    if (row < NN) C[(size_t)row * NCOLS + col] = v;
                }
            }
        }
    }

    if constexpr (STATS) {
        __shared__ float s_sum[128], s_sq[128];
        if (tid < 128) { s_sum[tid] = 0.f; s_sq[tid] = 0.f; }
        __syncthreads();
#pragma unroll
        for (int ni = 0; ni < 4; ++ni) {
            float a = psum[ni], q = psq[ni];
            a += __shfl_xor(a, 16); a += __shfl_xor(a, 32);
            q += __shfl_xor(q, 16); q += __shfl_xor(q, 32);
            if ((lane >> 4) == 0) {
                int cl = wn * 64 + ni * 16 + lane;
                atomicAdd(&s_sum[cl], a);
                atomicAdd(&s_sq[cl], q);
            }
        }
        __syncthreads();
        if (tid < 128) {
            atomicAdd(&statsOut[col0 + tid], s_sum[tid]);
            atomicAdd(&statsOut[256 + col0 + tid], s_sq[tid]);
        }
    }
}

extern "C" void kernel_launch(void* const* d_in, const int* in_sizes, int n_in,
                              void* d_out, int out_size, void* d_ws, size_t ws_size,
                              hipStream_t stream) {
    const float* feat  = (const float*)d_in[0];
    const int*   src   = (const int*)d_in[1];
    const int*   dst   = (const int*)d_in[2];
    const float* W0    = (const float*)d_in[3];
    const float* W1    = (const float*)d_in[4];
    const float* Wp1   = (const float*)d_in[5];
    const float* bp1   = (const float*)d_in[6];
    const float* gamma = (const float*)d_in[7];
    const float* beta  = (const float*)d_in[8];
    const float* Wp2   = (const float*)d_in[9];
    const float* bp2   = (const float*)d_in[10];
    float* out = (float*)d_out;

    char* wsb = (char*)d_ws;
    float* dinv   = (float*)(wsb + 4ull * 0);          // 50048
    int*   cnt    = (int*)  (wsb + 4ull * 50048);      // 50048
    int*   rowoff = (int*)  (wsb + 4ull * 100096);     // 50048
    int*   bsum   = (int*)  (wsb + 4ull * 150144);     // 256
    int*   boff   = (int*)  (wsb + 4ull * 150400);     // 256
    int*   pos    = (int*)  (wsb + 4ull * 150656);     // 800000
    int*   eidx   = (int*)  (wsb + 4ull * 950656);     // 800000
    float* stats  = (float*)(wsb + 4ull * 1750656);    // 512
    unsigned short* W0t  = (unsigned short*)(wsb + 4ull * 1751168);   // 65536 u16
    unsigned short* W1pt = W0t + 65536;                               // 32768 u16
    unsigned short* Wp2t = W1pt + 32768;                              // 32768 u16
    unsigned short* H0 = (unsigned short*)(wsb + 4ull * 1816704);     // [NNP][128] u16
    unsigned short* h1 = (unsigned short*)(wsb + 4ull * 5019776);
    unsigned short* h2 = H0;   // reuse after H0 consumed
    unsigned short* ZH = (unsigned short*)(wsb + 4ull * 8222848);     // [NNP][256] u16

    // ---- CSR build (count+slot assignment fused into wprep) ----
    hipMemsetAsync(cnt, 0, 50048 * sizeof(int), stream);
    k_wprep_count<<<512 + (NE + 255) / 256, 256, 0, stream>>>(
        W0, W1, Wp1, Wp2, W0t, W1pt, Wp2t, stats, dst, cnt, pos);
    k_bsum<<<NB, 256, 0, stream>>>(cnt, bsum);
    k_scan_bsum<<<1, 256, 0, stream>>>(bsum, boff);
    k_scan_block<<<NB, 256, 0, stream>>>(cnt, boff, rowoff, dinv);

    // H0 = feat @ W0 (bf16 out) FUSED with XCD-clustered atomic-free CSR fill
    k_gemm1_fill<<<NTOT, 512, 0, stream>>>(
        feat, W0t, H0, src, dst, rowoff, pos, eidx);

    // h1 = conv(H0); h2 = conv(h1)   [conv commutes with right-mult by W]
    k_gather_shfl<<<NNP / 4, 256, 0, stream>>>(H0, dinv, rowoff, cnt, eidx, h1);
    k_gather_shfl<<<NNP / 4, 256, 0, stream>>>(h1, dinv, rowoff, cnt, eidx, h2);

    // Z = h2 @ (W1@Wp1) + bp1  [NNP,256] bf16, fused BN column stats
    k_mfma<128, 256, true, 0, 1, true><<<dim3(GX, 2), 512, 0, stream>>>(
        h2, W1pt, bp1, nullptr, nullptr, nullptr, nullptr, ZH, stats);

    // out = relu(BN(Z)) @ Wp2 + bp2  (BN scale/shift precomputed per block in LDS)
    k_mfma<256, 128, true, 2, 0, false><<<dim3(GX, 1), 512, 0, stream>>>(
        ZH, Wp2t, bp2, stats, gamma, beta, out, nullptr, nullptr);
}

// Round 17
// 217.446 us; speedup vs baseline: 1.0798x; 1.0798x over previous
//
#include <hip/hip_runtime.h>
#include <math.h>

constexpr int NN  = 50000;
constexpr int NE  = 800000;
constexpr int NNP = 50048;             // padded rows = 391 * 128
constexpr int NB  = (NN + 255) / 256;  // scan blocks
constexpr int GX  = NNP / 128;         // 391 GEMM row tiles (gemm1, out-GEMM)
constexpr int GZ  = NNP / 64;          // 782 fused gather+GEMM-Z tiles
constexpr int FILLB = (NE + 511) / 512;

typedef __bf16 bf16x8 __attribute__((ext_vector_type(8)));
typedef float  f32x4  __attribute__((ext_vector_type(4)));
typedef __attribute__((address_space(1))) unsigned int as1_uint;
typedef __attribute__((address_space(3))) unsigned int as3_uint;

__device__ __forceinline__ unsigned short f2bf(float x) {  // RNE fp32->bf16 bits
    unsigned int u = __float_as_uint(x);
    return (unsigned short)((u + 0x7FFFu + ((u >> 16) & 1u)) >> 16);
}
__device__ __forceinline__ float bf2f(unsigned short h) {
    return __uint_as_float(((unsigned int)h) << 16);
}
__device__ __forceinline__ float rdlanef(float v, int j) {
    return __uint_as_float(__builtin_amdgcn_readlane(__float_as_uint(v), j));
}

__device__ __forceinline__ void gload16(const unsigned short* g, unsigned short* l) {
    __builtin_amdgcn_global_load_lds((const as1_uint*)(unsigned long long)g,
                                     (as3_uint*)(unsigned long long)l, 16, 0, 0);
}

// ---------------- CSR build ----------------
__global__ void k_bsum(const int* __restrict__ cnt, int* __restrict__ bsum) {
    int i = blockIdx.x * 256 + threadIdx.x;
    int v = (i < NN) ? cnt[i] : 0;
#pragma unroll
    for (int off = 32; off; off >>= 1) v += __shfl_down(v, off, 64);
    __shared__ int tmp[4];
    if ((threadIdx.x & 63) == 0) tmp[threadIdx.x >> 6] = v;
    __syncthreads();
    if (threadIdx.x == 0) bsum[blockIdx.x] = tmp[0] + tmp[1] + tmp[2] + tmp[3];
}

__global__ void k_scan_bsum(const int* __restrict__ bsum, int* __restrict__ boff) {
    __shared__ int s[256];
    int t = threadIdx.x;
    int v = (t < NB) ? bsum[t] : 0;
    s[t] = v;
    __syncthreads();
    for (int off = 1; off < 256; off <<= 1) {
        int u = (t >= off) ? s[t - off] : 0;
        __syncthreads();
        s[t] += u;
        __syncthreads();
    }
    if (t < NB) boff[t] = s[t] - v;
}

// also emits dinv (folded k_dinv)
__global__ void k_scan_block(const int* __restrict__ cnt, const int* __restrict__ boff,
                             int* __restrict__ rowoff, float* __restrict__ dinv) {
    __shared__ int s[256];
    int t = threadIdx.x;
    int i = blockIdx.x * 256 + t;
    int v = (i < NN) ? cnt[i] : 0;
    s[t] = v;
    __syncthreads();
    for (int off = 1; off < 256; off <<= 1) {
        int u = (t >= off) ? s[t - off] : 0;
        __syncthreads();
        s[t] += u;
        __syncthreads();
    }
    if (i < NN) {
        rowoff[i] = boff[blockIdx.x] + s[t] - v;
        dinv[i] = rsqrtf(fmaxf((float)v, 1.0f));
    }
}

// ---------------- shfl-broadcast low_conv gather (single bf16) ----------------
__global__ __launch_bounds__(256) void k_gather_shfl(
    const unsigned short* __restrict__ HH, const float* __restrict__ dinv,
    const int* __restrict__ rowoff, const int* __restrict__ cnt,
    const int* __restrict__ eidx, unsigned short* __restrict__ OH)
{
    int node = blockIdx.x * 4 + (threadIdx.x >> 6);
    int lane = threadIdx.x & 63;
    if (node >= NNP) return;
    size_t rb = (size_t)node * 128 + lane * 2;
    if (node >= NN) {  // zero pad rows
        *reinterpret_cast<ushort2*>(&OH[rb]) = make_ushort2(0, 0);
        return;
    }
    int beg = rowoff[node], n = cnt[node];
    int c2 = lane * 2;
    float ax = 0.f, ay = 0.f;
    for (int jj = 0; jj < n; jj += 64) {
        int m = min(n - jj, 64);
        int el = (lane < m) ? eidx[beg + jj + lane] : 0;   // pad lanes -> node 0
        float dl = dinv[el];
        int mp = (m + 7) & ~7;
        for (int j = 0; j < mp; j += 8) {
            int ss[8]; float dd[8]; ushort2 vv[8];
#pragma unroll
            for (int q = 0; q < 8; ++q) {
                int jq = (j + q) & 63;
                ss[q] = __builtin_amdgcn_readlane(el, jq);
                dd[q] = (j + q < m) ? rdlanef(dl, jq) : 0.f;   // uniform predicate
            }
#pragma unroll
            for (int q = 0; q < 8; ++q)
                vv[q] = *reinterpret_cast<const ushort2*>(&HH[(size_t)ss[q] * 128 + c2]);
#pragma unroll
            for (int q = 0; q < 8; ++q) {
                ax = fmaf(bf2f(vv[q].x), dd[q], ax);
                ay = fmaf(bf2f(vv[q].y), dd[q], ay);
            }
        }
    }
    float d = dinv[node];
    ushort2 sh = *reinterpret_cast<const ushort2*>(&HH[rb]);
    float hx = fmaf(ax, d, bf2f(sh.x));
    float hy = fmaf(ay, d, bf2f(sh.y));
    *reinterpret_cast<ushort2*>(&OH[rb]) = make_ushort2(f2bf(hx), f2bf(hy));
}

// ---------------- unified weight prep + dst histogram + slot assignment ----------------
__global__ void k_wprep_count(const float* __restrict__ W0, const float* __restrict__ W1,
                              const float* __restrict__ Wp1, const float* __restrict__ Wp2,
                              unsigned short* __restrict__ W0t, unsigned short* __restrict__ W1pt,
                              unsigned short* __restrict__ Wp2t, float* __restrict__ stats,
                              const int* __restrict__ dst, int* __restrict__ cnt,
                              int* __restrict__ pos) {
    int b = blockIdx.x, t = threadIdx.x;
    if (b >= 512) {
        int i = (b - 512) * 256 + t;
        if (i < NE) pos[i] = atomicAdd(&cnt[dst[i]], 1);
        return;
    }
    if (b < 128) {
        if (b < 2) stats[b * 256 + t] = 0.f;
        float s = 0.f;
        for (int k = 0; k < 128; ++k) s = fmaf(W1[b * 128 + k], Wp1[k * 256 + t], s);
        W1pt[t * 128 + b] = f2bf(s);
    } else if (b < 384) {
        int idx = (b - 128) * 256 + t;     // W0: K=512, N=128
        int k = idx >> 7, n = idx & 127;
        W0t[n * 512 + k] = f2bf(W0[idx]);
    } else {
        int idx = (b - 384) * 256 + t;     // Wp2: K=256, N=128
        int k = idx >> 7, n = idx & 127;
        Wp2t[n * 256 + k] = f2bf(Wp2[idx]);
    }
}

// ---------------- fused GEMM1 (feat@W0 -> bf16) + atomic-free CSR fill ----------------
__global__ __launch_bounds__(512) void k_gemm1_fill(
    const float* __restrict__ Af, const unsigned short* __restrict__ BH,
    unsigned short* __restrict__ OHs,
    const int* __restrict__ src, const int* __restrict__ dst,
    const int* __restrict__ rowoff, const int* __restrict__ pos,
    int* __restrict__ eidx)
{
    if (blockIdx.x >= GX) {   // ---- fill path (no atomics) ----
        int e = (blockIdx.x - GX) * 512 + threadIdx.x;
        if (e < NE) {
            int d = dst[e];
            eidx[rowoff[d] + pos[e]] = src[e];
        }
        return;
    }
    // ---- GEMM path (K=512, NCOLS=128) ----
    constexpr int K = 512, NCOLS = 128;
    __shared__ __align__(16) unsigned short lds[2 * 4096];
    unsigned short* ldsA = lds;
    unsigned short* ldsB = lds + 4096;

    const int tid  = threadIdx.x;
    const int lane = tid & 63;
    const int wid  = tid >> 6;
    const int wm   = wid >> 1;
    const int wn   = wid & 1;
    const int row0 = blockIdx.x * 128;

    const int srow  = tid >> 2;
    const int skg   = tid & 3;
    const int skswz = skg ^ ((srow >> 1) & 3);
    const size_t aSrc = (size_t)(row0 + srow) * K + skswz * 8;
    const size_t bSrc = (size_t)srow * K + skswz * 8;

    const int frow = lane & 15;
    const int fkg  = lane >> 4;

    f32x4 acc[2][4] = {};

    for (int k0 = 0; k0 < K; k0 += 32) {
        float4 f0, f1;
        if (row0 + srow < NN) {
            const float* ap = Af + aSrc + k0;
            f0 = *reinterpret_cast<const float4*>(ap);
            f1 = *reinterpret_cast<const float4*>(ap + 4);
        } else {
            f0 = make_float4(0.f, 0.f, 0.f, 0.f);
            f1 = f0;
        }
        uint4 w;
        w.x = (unsigned)f2bf(f0.x) | ((unsigned)f2bf(f0.y) << 16);
        w.y = (unsigned)f2bf(f0.z) | ((unsigned)f2bf(f0.w) << 16);
        w.z = (unsigned)f2bf(f1.x) | ((unsigned)f2bf(f1.y) << 16);
        w.w = (unsigned)f2bf(f1.z) | ((unsigned)f2bf(f1.w) << 16);
        *reinterpret_cast<uint4*>(&ldsA[tid * 8]) = w;
        gload16(BH + bSrc + k0, ldsB + tid * 8);
        __syncthreads();

        bf16x8 a_h[2], b_h[4];
#pragma unroll
        for (int mi = 0; mi < 2; ++mi) {
            int ar  = wm * 32 + mi * 16 + frow;
            int idx = ar * 32 + ((fkg ^ ((ar >> 1) & 3)) * 8);
            a_h[mi] = *reinterpret_cast<const bf16x8*>(&ldsA[idx]);
        }
#pragma unroll
        for (int ni = 0; ni < 4; ++ni) {
            int bc  = wn * 64 + ni * 16 + frow;
            int idx = bc * 32 + ((fkg ^ ((bc >> 1) & 3)) * 8);
            b_h[ni] = *reinterpret_cast<const bf16x8*>(&ldsB[idx]);
        }
#pragma unroll
        for (int mi = 0; mi < 2; ++mi)
#pragma unroll
            for (int ni = 0; ni < 4; ++ni)
                acc[mi][ni] = __builtin_amdgcn_mfma_f32_16x16x32_bf16(a_h[mi], b_h[ni], acc[mi][ni], 0, 0, 0);
        __syncthreads();
    }

#pragma unroll
    for (int mi = 0; mi < 2; ++mi) {
        int rbase = row0 + wm * 32 + mi * 16 + (lane >> 4) * 4;
#pragma unroll
        for (int ni = 0; ni < 4; ++ni) {
            int col = wn * 64 + ni * 16 + (lane & 15);
#pragma unroll
            for (int r = 0; r < 4; ++r)
                OHs[(size_t)(rbase + r) * NCOLS + col] = f2bf(acc[mi][ni][r]);
        }
    }
}

// ---------------- fused gather2 + GEMM-Z ----------------
// Each block: 64 output rows. Phase 1: gather h2 rows (conv of h1) straight into
// the swizzled LDS A-tile. Phase 2: Z = h2 @ W1pt + bp1 (K=128, NCOLS=256),
// bf16 Z out (pad rows incl.) + fused BN column stats.
__global__ __launch_bounds__(512) void k_gatherZ(
    const unsigned short* __restrict__ HH, const float* __restrict__ dinv,
    const int* __restrict__ rowoff, const int* __restrict__ cnt,
    const int* __restrict__ eidx, const unsigned short* __restrict__ W1pt,
    const float* __restrict__ bias, unsigned short* __restrict__ ZH,
    float* __restrict__ statsOut)
{
    __shared__ __align__(16) unsigned short ldsA[8192];   // 4 subtiles x 64 rows x 32
    __shared__ __align__(16) unsigned short ldsB[8192];   // 256 rows x 32 k (per step)
    __shared__ float s_sum[256], s_sq[256];

    const int tid  = threadIdx.x;
    const int lane = tid & 63;
    const int wid  = tid >> 6;
    const int row0 = blockIdx.x * 64;

    if (tid < 256) { s_sum[tid] = 0.f; s_sq[tid] = 0.f; }

    // ---- phase 1: gather 8 nodes per wave into swizzled A tile ----
    {
        int c = lane * 2;
        int sc = c >> 5, g = (c >> 3) & 3, e = c & 7;
        for (int it = 0; it < 8; ++it) {
            int r = wid * 8 + it;
            int node = row0 + r;
            int aaddr = sc * 2048 + r * 32 + ((g ^ ((r >> 1) & 3)) << 3) + e;
            if (node >= NN) {
                *reinterpret_cast<ushort2*>(&ldsA[aaddr]) = make_ushort2(0, 0);
                continue;
            }
            int beg = rowoff[node], n = cnt[node];
            float ax = 0.f, ay = 0.f;
            for (int jj = 0; jj < n; jj += 64) {
                int m = min(n - jj, 64);
                int el = (lane < m) ? eidx[beg + jj + lane] : 0;
                float dl = dinv[el];
                int mp = (m + 7) & ~7;
                for (int j = 0; j < mp; j += 8) {
                    int ss[8]; float dd[8]; ushort2 vv[8];
#pragma unroll
                    for (int q = 0; q < 8; ++q) {
                        int jq = (j + q) & 63;
                        ss[q] = __builtin_amdgcn_readlane(el, jq);
                        dd[q] = (j + q < m) ? rdlanef(dl, jq) : 0.f;
                    }
#pragma unroll
                    for (int q = 0; q < 8; ++q)
                        vv[q] = *reinterpret_cast<const ushort2*>(&HH[(size_t)ss[q] * 128 + c]);
#pragma unroll
                    for (int q = 0; q < 8; ++q) {
                        ax = fmaf(bf2f(vv[q].x), dd[q], ax);
                        ay = fmaf(bf2f(vv[q].y), dd[q], ay);
                    }
                }
            }
            float d = dinv[node];
            size_t rb = (size_t)node * 128 + c;
            ushort2 sh = *reinterpret_cast<const ushort2*>(&HH[rb]);
            float hx = fmaf(ax, d, bf2f(sh.x));
            float hy = fmaf(ay, d, bf2f(sh.y));
            *reinterpret_cast<ushort2*>(&ldsA[aaddr]) = make_ushort2(f2bf(hx), f2bf(hy));
        }
    }
    __syncthreads();

    // ---- phase 2: GEMM (K=128, NCOLS=256), wave = 32 rows x 64 cols ----
    const int wm = wid >> 2;      // 0..1
    const int wn = wid & 3;       // 0..3
    const int frow = lane & 15;
    const int fkg  = lane >> 4;
    f32x4 acc[2][4] = {};

    for (int k0 = 0; k0 < 128; k0 += 32) {
        // stage B: 256 rows x 32 k = 1024 slots of 16B; 512 threads x 2
        {
            int s1 = tid;
            int r1 = s1 >> 2, p1 = s1 & 3;
            gload16(W1pt + (size_t)r1 * 128 + k0 + ((p1 ^ ((r1 >> 1) & 3)) * 8),
                    ldsB + s1 * 8);
            int s2 = tid + 512;
            int r2 = s2 >> 2, p2 = s2 & 3;
            gload16(W1pt + (size_t)r2 * 128 + k0 + ((p2 ^ ((r2 >> 1) & 3)) * 8),
                    ldsB + s2 * 8);
        }
        __syncthreads();

        bf16x8 a_h[2], b_h[4];
        int sc = k0 >> 5;
#pragma unroll
        for (int mi = 0; mi < 2; ++mi) {
            int ar  = wm * 32 + mi * 16 + frow;
            int idx = sc * 2048 + ar * 32 + ((fkg ^ ((ar >> 1) & 3)) * 8);
            a_h[mi] = *reinterpret_cast<const bf16x8*>(&ldsA[idx]);
        }
#pragma unroll
        for (int ni = 0; ni < 4; ++ni) {
            int bc  = wn * 64 + ni * 16 + frow;
            int idx = bc * 32 + ((fkg ^ ((bc >> 1) & 3)) * 8);
            b_h[ni] = *reinterpret_cast<const bf16x8*>(&ldsB[idx]);
        }
#pragma unroll
        for (int mi = 0; mi < 2; ++mi)
#pragma unroll
            for (int ni = 0; ni < 4; ++ni)
                acc[mi][ni] = __builtin_amdgcn_mfma_f32_16x16x32_bf16(a_h[mi], b_h[ni], acc[mi][ni], 0, 0, 0);
        __syncthreads();
    }

    // ---- epilogue: bias + bf16 Z write (all rows) + BN stats (rows < NN) ----
    float psum[4] = {0.f, 0.f, 0.f, 0.f}, psq[4] = {0.f, 0.f, 0.f, 0.f};
#pragma unroll
    for (int mi = 0; mi < 2; ++mi) {
        int rbase = row0 + wm * 32 + mi * 16 + (lane >> 4) * 4;
#pragma unroll
        for (int ni = 0; ni < 4; ++ni) {
            int col = wn * 64 + ni * 16 + (lane & 15);
            float b = bias[col];
#pragma unroll
            for (int r = 0; r < 4; ++r) {
                int row = rbase + r;
                float v = acc[mi][ni][r] + b;
                if (row < NN) { psum[ni] += v; psq[ni] = fmaf(v, v, psq[ni]); }
                ZH[(size_t)row * 256 + col] = f2bf(v);
            }
        }
    }
#pragma unroll
    for (int ni = 0; ni < 4; ++ni) {
        float a = psum[ni], q = psq[ni];
        a += __shfl_xor(a, 16); a += __shfl_xor(a, 32);
        q += __shfl_xor(q, 16); q += __shfl_xor(q, 32);
        if ((lane >> 4) == 0) {
            int cl = wn * 64 + ni * 16 + lane;
            atomicAdd(&s_sum[cl], a);
            atomicAdd(&s_sq[cl], q);
        }
    }
    __syncthreads();
    if (tid < 256) {
        atomicAdd(&statsOut[tid], s_sum[tid]);
        atomicAdd(&statsOut[256 + tid], s_sq[tid]);
    }
}

// ---------------- single-bf16 MFMA GEMM (out-GEMM only) ----------------
// AMODE 2: bf16 reg-staged + BN+ReLU (scale/shift precomputed per block in LDS).
template <int K, int NCOLS, bool BIAS, int AMODE, int OMODE, bool STATS>
__global__ __launch_bounds__(512) void k_mfma(
    const unsigned short* __restrict__ AH, const unsigned short* __restrict__ BH,
    const float* __restrict__ bias,
    const float* __restrict__ stats, const float* __restrict__ gamma,
    const float* __restrict__ beta,
    float* __restrict__ C, unsigned short* __restrict__ OHs,
    float* __restrict__ statsOut)
{
    __shared__ __align__(16) unsigned short lds[2 * 4096];
    unsigned short* ldsA = lds;
    unsigned short* ldsB = lds + 4096;

    const int tid  = threadIdx.x;
    const int lane = tid & 63;
    const int wid  = tid >> 6;
    const int wm   = wid >> 1;
    const int wn   = wid & 1;
    const int row0 = blockIdx.x * 128;
    const int col0 = blockIdx.y * 128;

    const int srow  = tid >> 2;
    const int skg   = tid & 3;
    const int skswz = skg ^ ((srow >> 1) & 3);
    const size_t aSrc = (size_t)(row0 + srow) * K + skswz * 8;
    const size_t bSrc = (size_t)(col0 + srow) * K + skswz * 8;

    const int frow = lane & 15;
    const int fkg  = lane >> 4;

    __shared__ float s_scl[256], s_shf[256];
    if constexpr (AMODE == 2) {
        if (tid < K) {
            float mu  = stats[tid] * (1.0f / NN);
            float var = stats[256 + tid] * (1.0f / NN) - mu * mu;
            float s = gamma[tid] * rsqrtf(var + 1e-5f);
            s_scl[tid] = s;
            s_shf[tid] = beta[tid] - mu * s;
        }
        __syncthreads();
    }

    f32x4 acc[2][4] = {};

    for (int k0 = 0; k0 < K; k0 += 32) {
        if constexpr (AMODE == 2) {
            uint4 raw = *reinterpret_cast<const uint4*>(&AH[aSrc + k0]);
            unsigned rw[4] = {raw.x, raw.y, raw.z, raw.w};
            int kc = k0 + skswz * 8;
            float vv[8];
#pragma unroll
            for (int q = 0; q < 8; ++q) {
                float z = bf2f((unsigned short)((q & 1) ? (rw[q >> 1] >> 16)
                                                        : (rw[q >> 1] & 0xFFFF)));
                vv[q] = fmaxf(fmaf(z, s_scl[kc + q], s_shf[kc + q]), 0.f);
            }
            uint4 w;
            w.x = (unsigned)f2bf(vv[0]) | ((unsigned)f2bf(vv[1]) << 16);
            w.y = (unsigned)f2bf(vv[2]) | ((unsigned)f2bf(vv[3]) << 16);
            w.z = (unsigned)f2bf(vv[4]) | ((unsigned)f2bf(vv[5]) << 16);
            w.w = (unsigned)f2bf(vv[6]) | ((unsigned)f2bf(vv[7]) << 16);
            *reinterpret_cast<uint4*>(&ldsA[tid * 8]) = w;
        } else {
            gload16(AH + aSrc + k0, ldsA + tid * 8);
        }
        gload16(BH + bSrc + k0, ldsB + tid * 8);
        __syncthreads();

        bf16x8 a_h[2], b_h[4];
#pragma unroll
        for (int mi = 0; mi < 2; ++mi) {
            int ar  = wm * 32 + mi * 16 + frow;
            int idx = ar * 32 + ((fkg ^ ((ar >> 1) & 3)) * 8);
            a_h[mi] = *reinterpret_cast<const bf16x8*>(&ldsA[idx]);
        }
#pragma unroll
        for (int ni = 0; ni < 4; ++ni) {
            int bc  = wn * 64 + ni * 16 + frow;
            int idx = bc * 32 + ((fkg ^ ((bc >> 1) & 3)) * 8);
            b_h[ni] = *reinterpret_cast<const bf16x8*>(&ldsB[idx]);
        }
#pragma unroll
        for (int mi = 0; mi < 2; ++mi)
#pragma unroll
            for (int ni = 0; ni < 4; ++ni)
                acc[mi][ni] = __builtin_amdgcn_mfma_f32_16x16x32_bf16(a_h[mi], b_h[ni], acc[mi][ni], 0, 0, 0);
        __syncthreads();
    }

#pragma unroll
    for (int mi = 0; mi < 2; ++mi) {
        int rbase = row0 + wm * 32 + mi * 16 + (lane >> 4) * 4;
#pragma unroll
        for (int ni = 0; ni < 4; ++ni) {
            int col = col0 + wn * 64 + ni * 16 + (lane & 15);
            float b = BIAS ? bias[col] : 0.f;
#pragma unroll
            for (int r = 0; r < 4; ++r) {
                int row = rbase + r;
                float v = acc[mi][ni][r] + b;
                if (row < NN) C[(size_t)row * NCOLS + col] = v;
            }
        }
    }
}

extern "C" void kernel_launch(void* const* d_in, const int* in_sizes, int n_in,
                              void* d_out, int out_size, void* d_ws, size_t ws_size,
                              hipStream_t stream) {
    const float* feat  = (const float*)d_in[0];
    const int*   src   = (const int*)d_in[1];
    const int*   dst   = (const int*)d_in[2];
    const float* W0    = (const float*)d_in[3];
    const float* W1    = (const float*)d_in[4];
    const float* Wp1   = (const float*)d_in[5];
    const float* bp1   = (const float*)d_in[6];
    const float* gamma = (const float*)d_in[7];
    const float* beta  = (const float*)d_in[8];
    const float* Wp2   = (const float*)d_in[9];
    const float* bp2   = (const float*)d_in[10];
    float* out = (float*)d_out;

    char* wsb = (char*)d_ws;
    float* dinv   = (float*)(wsb + 4ull * 0);          // 50048
    int*   cnt    = (int*)  (wsb + 4ull * 50048);      // 50048
    int*   rowoff = (int*)  (wsb + 4ull * 100096);     // 50048
    int*   bsum   = (int*)  (wsb + 4ull * 150144);     // 256
    int*   boff   = (int*)  (wsb + 4ull * 150400);     // 256
    int*   pos    = (int*)  (wsb + 4ull * 150656);     // 800000
    int*   eidx   = (int*)  (wsb + 4ull * 950656);     // 800000
    float* stats  = (float*)(wsb + 4ull * 1750656);    // 512
    unsigned short* W0t  = (unsigned short*)(wsb + 4ull * 1751168);   // 65536 u16
    unsigned short* W1pt = W0t + 65536;                               // 32768 u16
    unsigned short* Wp2t = W1pt + 32768;                              // 32768 u16
    unsigned short* H0 = (unsigned short*)(wsb + 4ull * 1816704);     // [NNP][128] u16
    unsigned short* h1 = (unsigned short*)(wsb + 4ull * 5019776);
    unsigned short* ZH = (unsigned short*)(wsb + 4ull * 8222848);     // [NNP][256] u16

    // ---- CSR build (count+slot assignment fused into wprep) ----
    hipMemsetAsync(cnt, 0, 50048 * sizeof(int), stream);
    k_wprep_count<<<512 + (NE + 255) / 256, 256, 0, stream>>>(
        W0, W1, Wp1, Wp2, W0t, W1pt, Wp2t, stats, dst, cnt, pos);
    k_bsum<<<NB, 256, 0, stream>>>(cnt, bsum);
    k_scan_bsum<<<1, 256, 0, stream>>>(bsum, boff);
    k_scan_block<<<NB, 256, 0, stream>>>(cnt, boff, rowoff, dinv);

    // H0 = feat @ W0 (bf16 out) FUSED with atomic-free CSR eidx fill
    k_gemm1_fill<<<GX + FILLB, 512, 0, stream>>>(
        feat, W0t, H0, src, dst, rowoff, pos, eidx);

    // h1 = conv(H0)
    k_gather_shfl<<<NNP / 4, 256, 0, stream>>>(H0, dinv, rowoff, cnt, eidx, h1);

    // Z = conv(h1) @ W1pt + bp1  — gather2 fused into GEMM-Z (+ BN stats)
    k_gatherZ<<<GZ, 512, 0, stream>>>(h1, dinv, rowoff, cnt, eidx, W1pt, bp1, ZH, stats);

    // out = relu(BN(Z)) @ Wp2 + bp2  (BN scale/shift precomputed per block in LDS)
    k_mfma<256, 128, true, 2, 0, false><<<dim3(GX, 1), 512, 0, stream>>>(
        ZH, Wp2t, bp2, stats, gamma, beta, out, nullptr, nullptr);
}

// Round 18
// 197.437 us; speedup vs baseline: 1.1892x; 1.1013x over previous
//
#include <hip/hip_runtime.h>
#include <math.h>

constexpr int NN  = 50000;
constexpr int NE  = 800000;
constexpr int NNP = 50048;             // padded rows = 391 * 128
constexpr int NB  = (NN + 255) / 256;  // scan blocks
constexpr int GX  = NNP / 128;         // 391 GEMM row tiles
constexpr int FILLB = (NE + 511) / 512;

typedef __bf16 bf16x8 __attribute__((ext_vector_type(8)));
typedef float  f32x4  __attribute__((ext_vector_type(4)));
typedef __attribute__((address_space(1))) unsigned int as1_uint;
typedef __attribute__((address_space(3))) unsigned int as3_uint;

__device__ __forceinline__ unsigned short f2bf(float x) {  // RNE fp32->bf16 bits
    unsigned int u = __float_as_uint(x);
    return (unsigned short)((u + 0x7FFFu + ((u >> 16) & 1u)) >> 16);
}
__device__ __forceinline__ float bf2f(unsigned short h) {
    return __uint_as_float(((unsigned int)h) << 16);
}
__device__ __forceinline__ float rdlanef(float v, int j) {
    return __uint_as_float(__builtin_amdgcn_readlane(__float_as_uint(v), j));
}

__device__ __forceinline__ void gload16(const unsigned short* g, unsigned short* l) {
    __builtin_amdgcn_global_load_lds((const as1_uint*)(unsigned long long)g,
                                     (as3_uint*)(unsigned long long)l, 16, 0, 0);
}

// ---------------- CSR build ----------------
__global__ void k_bsum(const int* __restrict__ cnt, int* __restrict__ bsum) {
    int i = blockIdx.x * 256 + threadIdx.x;
    int v = (i < NN) ? cnt[i] : 0;
#pragma unroll
    for (int off = 32; off; off >>= 1) v += __shfl_down(v, off, 64);
    __shared__ int tmp[4];
    if ((threadIdx.x & 63) == 0) tmp[threadIdx.x >> 6] = v;
    __syncthreads();
    if (threadIdx.x == 0) bsum[blockIdx.x] = tmp[0] + tmp[1] + tmp[2] + tmp[3];
}

__global__ void k_scan_bsum(const int* __restrict__ bsum, int* __restrict__ boff) {
    __shared__ int s[256];
    int t = threadIdx.x;
    int v = (t < NB) ? bsum[t] : 0;
    s[t] = v;
    __syncthreads();
    for (int off = 1; off < 256; off <<= 1) {
        int u = (t >= off) ? s[t - off] : 0;
        __syncthreads();
        s[t] += u;
        __syncthreads();
    }
    if (t < NB) boff[t] = s[t] - v;
}

// also emits dinv (folded k_dinv)
__global__ void k_scan_block(const int* __restrict__ cnt, const int* __restrict__ boff,
                             int* __restrict__ rowoff, float* __restrict__ dinv) {
    __shared__ int s[256];
    int t = threadIdx.x;
    int i = blockIdx.x * 256 + t;
    int v = (i < NN) ? cnt[i] : 0;
    s[t] = v;
    __syncthreads();
    for (int off = 1; off < 256; off <<= 1) {
        int u = (t >= off) ? s[t - off] : 0;
        __syncthreads();
        s[t] += u;
        __syncthreads();
    }
    if (i < NN) {
        rowoff[i] = boff[blockIdx.x] + s[t] - v;
        dinv[i] = rsqrtf(fmaxf((float)v, 1.0f));
    }
}

// ---------------- shfl-broadcast low_conv gather (single bf16) ----------------
// wave = 1 node, 64 lanes x ushort2 = full 256B row per load. eidx+dinv preloaded
// lane-parallel, broadcast via readlane. Predicated groups of 8 (no serial tail).
__global__ __launch_bounds__(256) void k_gather_shfl(
    const unsigned short* __restrict__ HH, const float* __restrict__ dinv,
    const int* __restrict__ rowoff, const int* __restrict__ cnt,
    const int* __restrict__ eidx, unsigned short* __restrict__ OH)
{
    int node = blockIdx.x * 4 + (threadIdx.x >> 6);
    int lane = threadIdx.x & 63;
    if (node >= NNP) return;
    size_t rb = (size_t)node * 128 + lane * 2;
    if (node >= NN) {  // zero pad rows
        *reinterpret_cast<ushort2*>(&OH[rb]) = make_ushort2(0, 0);
        return;
    }
    int beg = rowoff[node], n = cnt[node];
    int c2 = lane * 2;
    float ax = 0.f, ay = 0.f;
    for (int jj = 0; jj < n; jj += 64) {
        int m = min(n - jj, 64);
        int el = (lane < m) ? eidx[beg + jj + lane] : 0;   // pad lanes -> node 0
        float dl = dinv[el];
        int mp = (m + 7) & ~7;
        for (int j = 0; j < mp; j += 8) {
            int ss[8]; float dd[8]; ushort2 vv[8];
#pragma unroll
            for (int q = 0; q < 8; ++q) {
                int jq = (j + q) & 63;
                ss[q] = __builtin_amdgcn_readlane(el, jq);
                dd[q] = (j + q < m) ? rdlanef(dl, jq) : 0.f;   // uniform predicate
            }
#pragma unroll
            for (int q = 0; q < 8; ++q)
                vv[q] = *reinterpret_cast<const ushort2*>(&HH[(size_t)ss[q] * 128 + c2]);
#pragma unroll
            for (int q = 0; q < 8; ++q) {
                ax = fmaf(bf2f(vv[q].x), dd[q], ax);
                ay = fmaf(bf2f(vv[q].y), dd[q], ay);
            }
        }
    }
    float d = dinv[node];
    ushort2 sh = *reinterpret_cast<const ushort2*>(&HH[rb]);
    float hx = fmaf(ax, d, bf2f(sh.x));
    float hy = fmaf(ay, d, bf2f(sh.y));
    *reinterpret_cast<ushort2*>(&OH[rb]) = make_ushort2(f2bf(hx), f2bf(hy));
}

// ---------------- unified weight prep + dst histogram + slot assignment ----------------
__global__ void k_wprep_count(const float* __restrict__ W0, const float* __restrict__ W1,
                              const float* __restrict__ Wp1, const float* __restrict__ Wp2,
                              unsigned short* __restrict__ W0t, unsigned short* __restrict__ W1pt,
                              unsigned short* __restrict__ Wp2t, float* __restrict__ stats,
                              const int* __restrict__ dst, int* __restrict__ cnt,
                              int* __restrict__ pos) {
    int b = blockIdx.x, t = threadIdx.x;
    if (b >= 512) {
        int i = (b - 512) * 256 + t;
        if (i < NE) pos[i] = atomicAdd(&cnt[dst[i]], 1);
        return;
    }
    if (b < 128) {
        if (b < 2) stats[b * 256 + t] = 0.f;
        float s = 0.f;
        for (int k = 0; k < 128; ++k) s = fmaf(W1[b * 128 + k], Wp1[k * 256 + t], s);
        W1pt[t * 128 + b] = f2bf(s);
    } else if (b < 384) {
        int idx = (b - 128) * 256 + t;     // W0: K=512, N=128
        int k = idx >> 7, n = idx & 127;
        W0t[n * 512 + k] = f2bf(W0[idx]);
    } else {
        int idx = (b - 384) * 256 + t;     // Wp2: K=256, N=128
        int k = idx >> 7, n = idx & 127;
        Wp2t[n * 256 + k] = f2bf(Wp2[idx]);
    }
}

// ---------------- fused GEMM1 (feat@W0 -> bf16) + atomic-free CSR fill ----------------
__global__ __launch_bounds__(512) void k_gemm1_fill(
    const float* __restrict__ Af, const unsigned short* __restrict__ BH,
    unsigned short* __restrict__ OHs,
    const int* __restrict__ src, const int* __restrict__ dst,
    const int* __restrict__ rowoff, const int* __restrict__ pos,
    int* __restrict__ eidx)
{
    if (blockIdx.x >= GX) {   // ---- fill path (no atomics) ----
        int e = (blockIdx.x - GX) * 512 + threadIdx.x;
        if (e < NE) {
            int d = dst[e];
            eidx[rowoff[d] + pos[e]] = src[e];
        }
        return;
    }
    // ---- GEMM path (K=512, NCOLS=128) ----
    constexpr int K = 512, NCOLS = 128;
    __shared__ __align__(16) unsigned short lds[2 * 4096];
    unsigned short* ldsA = lds;
    unsigned short* ldsB = lds + 4096;

    const int tid  = threadIdx.x;
    const int lane = tid & 63;
    const int wid  = tid >> 6;
    const int wm   = wid >> 1;
    const int wn   = wid & 1;
    const int row0 = blockIdx.x * 128;

    const int srow  = tid >> 2;
    const int skg   = tid & 3;
    const int skswz = skg ^ ((srow >> 1) & 3);
    const size_t aSrc = (size_t)(row0 + srow) * K + skswz * 8;
    const size_t bSrc = (size_t)srow * K + skswz * 8;

    const int frow = lane & 15;
    const int fkg  = lane >> 4;

    f32x4 acc[2][4] = {};

    for (int k0 = 0; k0 < K; k0 += 32) {
        float4 f0, f1;
        if (row0 + srow < NN) {
            const float* ap = Af + aSrc + k0;
            f0 = *reinterpret_cast<const float4*>(ap);
            f1 = *reinterpret_cast<const float4*>(ap + 4);
        } else {
            f0 = make_float4(0.f, 0.f, 0.f, 0.f);
            f1 = f0;
        }
        uint4 w;
        w.x = (unsigned)f2bf(f0.x) | ((unsigned)f2bf(f0.y) << 16);
        w.y = (unsigned)f2bf(f0.z) | ((unsigned)f2bf(f0.w) << 16);
        w.z = (unsigned)f2bf(f1.x) | ((unsigned)f2bf(f1.y) << 16);
        w.w = (unsigned)f2bf(f1.z) | ((unsigned)f2bf(f1.w) << 16);
        *reinterpret_cast<uint4*>(&ldsA[tid * 8]) = w;
        gload16(BH + bSrc + k0, ldsB + tid * 8);
        __syncthreads();

        bf16x8 a_h[2], b_h[4];
#pragma unroll
        for (int mi = 0; mi < 2; ++mi) {
            int ar  = wm * 32 + mi * 16 + frow;
            int idx = ar * 32 + ((fkg ^ ((ar >> 1) & 3)) * 8);
            a_h[mi] = *reinterpret_cast<const bf16x8*>(&ldsA[idx]);
        }
#pragma unroll
        for (int ni = 0; ni < 4; ++ni) {
            int bc  = wn * 64 + ni * 16 + frow;
            int idx = bc * 32 + ((fkg ^ ((bc >> 1) & 3)) * 8);
            b_h[ni] = *reinterpret_cast<const bf16x8*>(&ldsB[idx]);
        }
#pragma unroll
        for (int mi = 0; mi < 2; ++mi)
#pragma unroll
            for (int ni = 0; ni < 4; ++ni)
                acc[mi][ni] = __builtin_amdgcn_mfma_f32_16x16x32_bf16(a_h[mi], b_h[ni], acc[mi][ni], 0, 0, 0);
        __syncthreads();
    }

#pragma unroll
    for (int mi = 0; mi < 2; ++mi) {
        int rbase = row0 + wm * 32 + mi * 16 + (lane >> 4) * 4;
#pragma unroll
        for (int ni = 0; ni < 4; ++ni) {
            int col = wn * 64 + ni * 16 + (lane & 15);
#pragma unroll
            for (int r = 0; r < 4; ++r)
                OHs[(size_t)(rbase + r) * NCOLS + col] = f2bf(acc[mi][ni][r]);
        }
    }
}

// ---------------- single-bf16 MFMA GEMM (flat layouts) ----------------
// AMODE: 0 = bf16 via global_load_lds; 2 = bf16 reg-staged + BN+ReLU (LDS-precomputed).
// OMODE: 0 = fp32 C (rows<NN); 1 = bf16 all rows. STATS: column sum/sumsq (rows<NN).
template <int K, int NCOLS, bool BIAS, int AMODE, int OMODE, bool STATS>
__global__ __launch_bounds__(512) void k_mfma(
    const unsigned short* __restrict__ AH, const unsigned short* __restrict__ BH,
    const float* __restrict__ bias,
    const float* __restrict__ stats, const float* __restrict__ gamma,
    const float* __restrict__ beta,
    float* __restrict__ C, unsigned short* __restrict__ OHs,
    float* __restrict__ statsOut)
{
    __shared__ __align__(16) unsigned short lds[2 * 4096];
    unsigned short* ldsA = lds;
    unsigned short* ldsB = lds + 4096;

    const int tid  = threadIdx.x;
    const int lane = tid & 63;
    const int wid  = tid >> 6;
    const int wm   = wid >> 1;
    const int wn   = wid & 1;
    const int row0 = blockIdx.x * 128;
    const int col0 = blockIdx.y * 128;

    const int srow  = tid >> 2;
    const int skg   = tid & 3;
    const int skswz = skg ^ ((srow >> 1) & 3);
    const size_t aSrc = (size_t)(row0 + srow) * K + skswz * 8;
    const size_t bSrc = (size_t)(col0 + srow) * K + skswz * 8;

    const int frow = lane & 15;
    const int fkg  = lane >> 4;

    __shared__ float s_scl[256], s_shf[256];
    if constexpr (AMODE == 2) {
        if (tid < K) {
            float mu  = stats[tid] * (1.0f / NN);
            float var = stats[256 + tid] * (1.0f / NN) - mu * mu;
            float s = gamma[tid] * rsqrtf(var + 1e-5f);
            s_scl[tid] = s;
            s_shf[tid] = beta[tid] - mu * s;
        }
        __syncthreads();
    }

    f32x4 acc[2][4] = {};

    for (int k0 = 0; k0 < K; k0 += 32) {
        if constexpr (AMODE == 2) {
            uint4 raw = *reinterpret_cast<const uint4*>(&AH[aSrc + k0]);
            unsigned rw[4] = {raw.x, raw.y, raw.z, raw.w};
            int kc = k0 + skswz * 8;
            float vv[8];
#pragma unroll
            for (int q = 0; q < 8; ++q) {
                float z = bf2f((unsigned short)((q & 1) ? (rw[q >> 1] >> 16)
                                                        : (rw[q >> 1] & 0xFFFF)));
                vv[q] = fmaxf(fmaf(z, s_scl[kc + q], s_shf[kc + q]), 0.f);
            }
            uint4 w;
            w.x = (unsigned)f2bf(vv[0]) | ((unsigned)f2bf(vv[1]) << 16);
            w.y = (unsigned)f2bf(vv[2]) | ((unsigned)f2bf(vv[3]) << 16);
            w.z = (unsigned)f2bf(vv[4]) | ((unsigned)f2bf(vv[5]) << 16);
            w.w = (unsigned)f2bf(vv[6]) | ((unsigned)f2bf(vv[7]) << 16);
            *reinterpret_cast<uint4*>(&ldsA[tid * 8]) = w;
        } else {
            gload16(AH + aSrc + k0, ldsA + tid * 8);
        }
        gload16(BH + bSrc + k0, ldsB + tid * 8);
        __syncthreads();

        bf16x8 a_h[2], b_h[4];
#pragma unroll
        for (int mi = 0; mi < 2; ++mi) {
            int ar  = wm * 32 + mi * 16 + frow;
            int idx = ar * 32 + ((fkg ^ ((ar >> 1) & 3)) * 8);
            a_h[mi] = *reinterpret_cast<const bf16x8*>(&ldsA[idx]);
        }
#pragma unroll
        for (int ni = 0; ni < 4; ++ni) {
            int bc  = wn * 64 + ni * 16 + frow;
            int idx = bc * 32 + ((fkg ^ ((bc >> 1) & 3)) * 8);
            b_h[ni] = *reinterpret_cast<const bf16x8*>(&ldsB[idx]);
        }
#pragma unroll
        for (int mi = 0; mi < 2; ++mi)
#pragma unroll
            for (int ni = 0; ni < 4; ++ni)
                acc[mi][ni] = __builtin_amdgcn_mfma_f32_16x16x32_bf16(a_h[mi], b_h[ni], acc[mi][ni], 0, 0, 0);
        __syncthreads();
    }

    float psum[4] = {0.f, 0.f, 0.f, 0.f}, psq[4] = {0.f, 0.f, 0.f, 0.f};
#pragma unroll
    for (int mi = 0; mi < 2; ++mi) {
        int rbase = row0 + wm * 32 + mi * 16 + (lane >> 4) * 4;
#pragma unroll
        for (int ni = 0; ni < 4; ++ni) {
            int col = col0 + wn * 64 + ni * 16 + (lane & 15);
            float b = BIAS ? bias[col] : 0.f;
#pragma unroll
            for (int r = 0; r < 4; ++r) {
                int row = rbase + r;
                float v = acc[mi][ni][r] + b;
                if constexpr (STATS) {
                    if (row < NN) { psum[ni] += v; psq[ni] = fmaf(v, v, psq[ni]); }
                }
                if constexpr (OMODE == 1) {
                    OHs[(size_t)row * NCOLS + col] = f2bf(v);   // pad rows too
                } else {
                    if (row < NN) C[(size_t)row * NCOLS + col] = v;
                }
            }
        }
    }

    if constexpr (STATS) {
        __shared__ float s_sum[128], s_sq[128];
        if (tid < 128) { s_sum[tid] = 0.f; s_sq[tid] = 0.f; }
        __syncthreads();
#pragma unroll
        for (int ni = 0; ni < 4; ++ni) {
            float a = psum[ni], q = psq[ni];
            a += __shfl_xor(a, 16); a += __shfl_xor(a, 32);
            q += __shfl_xor(q, 16); q += __shfl_xor(q, 32);
            if ((lane >> 4) == 0) {
                int cl = wn * 64 + ni * 16 + lane;
                atomicAdd(&s_sum[cl], a);
                atomicAdd(&s_sq[cl], q);
            }
        }
        __syncthreads();
        if (tid < 128) {
            atomicAdd(&statsOut[col0 + tid], s_sum[tid]);
            atomicAdd(&statsOut[256 + col0 + tid], s_sq[tid]);
        }
    }
}

extern "C" void kernel_launch(void* const* d_in, const int* in_sizes, int n_in,
                              void* d_out, int out_size, void* d_ws, size_t ws_size,
                              hipStream_t stream) {
    const float* feat  = (const float*)d_in[0];
    const int*   src   = (const int*)d_in[1];
    const int*   dst   = (const int*)d_in[2];
    const float* W0    = (const float*)d_in[3];
    const float* W1    = (const float*)d_in[4];
    const float* Wp1   = (const float*)d_in[5];
    const float* bp1   = (const float*)d_in[6];
    const float* gamma = (const float*)d_in[7];
    const float* beta  = (const float*)d_in[8];
    const float* Wp2   = (const float*)d_in[9];
    const float* bp2   = (const float*)d_in[10];
    float* out = (float*)d_out;

    char* wsb = (char*)d_ws;
    float* dinv   = (float*)(wsb + 4ull * 0);          // 50048
    int*   cnt    = (int*)  (wsb + 4ull * 50048);      // 50048
    int*   rowoff = (int*)  (wsb + 4ull * 100096);     // 50048
    int*   bsum   = (int*)  (wsb + 4ull * 150144);     // 256
    int*   boff   = (int*)  (wsb + 4ull * 150400);     // 256
    int*   pos    = (int*)  (wsb + 4ull * 150656);     // 800000
    int*   eidx   = (int*)  (wsb + 4ull * 950656);     // 800000
    float* stats  = (float*)(wsb + 4ull * 1750656);    // 512
    unsigned short* W0t  = (unsigned short*)(wsb + 4ull * 1751168);   // 65536 u16
    unsigned short* W1pt = W0t + 65536;                               // 32768 u16
    unsigned short* Wp2t = W1pt + 32768;                              // 32768 u16
    unsigned short* H0 = (unsigned short*)(wsb + 4ull * 1816704);     // [NNP][128] u16
    unsigned short* h1 = (unsigned short*)(wsb + 4ull * 5019776);
    unsigned short* h2 = H0;   // reuse after H0 consumed
    unsigned short* ZH = (unsigned short*)(wsb + 4ull * 8222848);     // [NNP][256] u16

    // ---- CSR build (count+slot assignment fused into wprep) ----
    hipMemsetAsync(cnt, 0, 50048 * sizeof(int), stream);
    k_wprep_count<<<512 + (NE + 255) / 256, 256, 0, stream>>>(
        W0, W1, Wp1, Wp2, W0t, W1pt, Wp2t, stats, dst, cnt, pos);
    k_bsum<<<NB, 256, 0, stream>>>(cnt, bsum);
    k_scan_bsum<<<1, 256, 0, stream>>>(bsum, boff);
    k_scan_block<<<NB, 256, 0, stream>>>(cnt, boff, rowoff, dinv);

    // H0 = feat @ W0 (bf16 out) FUSED with atomic-free CSR eidx fill
    k_gemm1_fill<<<GX + FILLB, 512, 0, stream>>>(
        feat, W0t, H0, src, dst, rowoff, pos, eidx);

    // h1 = conv(H0); h2 = conv(h1)   [conv commutes with right-mult by W]
    k_gather_shfl<<<NNP / 4, 256, 0, stream>>>(H0, dinv, rowoff, cnt, eidx, h1);
    k_gather_shfl<<<NNP / 4, 256, 0, stream>>>(h1, dinv, rowoff, cnt, eidx, h2);

    // Z = h2 @ (W1@Wp1) + bp1  [NNP,256] bf16, fused BN column stats
    k_mfma<128, 256, true, 0, 1, true><<<dim3(GX, 2), 512, 0, stream>>>(
        h2, W1pt, bp1, nullptr, nullptr, nullptr, nullptr, ZH, stats);

    // out = relu(BN(Z)) @ Wp2 + bp2  (BN scale/shift precomputed per block in LDS)
    k_mfma<256, 128, true, 2, 0, false><<<dim3(GX, 1), 512, 0, stream>>>(
        ZH, Wp2t, bp2, stats, gamma, beta, out, nullptr, nullptr);
}